// Round 1
// baseline (5054.938 us; speedup 1.0000x reference)
//
#include <hip/hip_runtime.h>
#include <math.h>

#define Bz 4
#define Lz 4096
#define Dz 1024
#define Hz 16
#define Cz 8
#define Sz 512
#define DHz 64

__device__ __forceinline__ float sigmaf(float x) {
    return x >= 0.f ? x : expm1f(x);
}

// ---------------- QKV projection: out = X @ W + b  (3 GEMMs via blockIdx.z) ----
__global__ __launch_bounds__(256) void proj_kernel(
    const float* __restrict__ Xq, const float* __restrict__ Xk, const float* __restrict__ Xv,
    const float* __restrict__ Wq, const float* __restrict__ bq,
    const float* __restrict__ Wk, const float* __restrict__ bk,
    const float* __restrict__ Wv, const float* __restrict__ bv,
    float* __restrict__ outq, float* __restrict__ outk, float* __restrict__ outv)
{
    const int which = blockIdx.z;
    const float* __restrict__ X = which == 0 ? Xq : (which == 1 ? Xk : Xv);
    const float* __restrict__ W = which == 0 ? Wq : (which == 1 ? Wk : Wv);
    const float* __restrict__ bias = which == 0 ? bq : (which == 1 ? bk : bv);
    float* __restrict__ out = which == 0 ? outq : (which == 1 ? outk : outv);

    __shared__ float As[16][64];   // [k][m]
    __shared__ float Bs[16][64];   // [k][n]
    const int tid = threadIdx.x;
    const int m0 = blockIdx.y * 64;
    const int n0 = blockIdx.x * 64;
    const int tx = tid & 15, ty = tid >> 4;

    float acc[4][4] = {{0.f}};

    const int lm = tid >> 2;          // A row 0..63
    const int lk = (tid & 3) * 4;     // A k 0,4,8,12
    const int br = tid >> 4;          // B row 0..15
    const int bn = (tid & 15) * 4;    // B col

    for (int k0 = 0; k0 < Dz; k0 += 16) {
        float4 a = *(const float4*)&X[(size_t)(m0 + lm) * Dz + k0 + lk];
        float4 b4 = *(const float4*)&W[(size_t)(k0 + br) * Dz + n0 + bn];
        __syncthreads();
        As[lk + 0][lm] = a.x; As[lk + 1][lm] = a.y; As[lk + 2][lm] = a.z; As[lk + 3][lm] = a.w;
        *(float4*)&Bs[br][bn] = b4;
        __syncthreads();
#pragma unroll
        for (int kk = 0; kk < 16; ++kk) {
            float av[4], bv4[4];
            *(float4*)av  = *(const float4*)&As[kk][ty * 4];
            *(float4*)bv4 = *(const float4*)&Bs[kk][tx * 4];
#pragma unroll
            for (int i = 0; i < 4; ++i)
#pragma unroll
                for (int j = 0; j < 4; ++j) acc[i][j] += av[i] * bv4[j];
        }
    }
#pragma unroll
    for (int i = 0; i < 4; ++i) {
        int m = m0 + ty * 4 + i;
        float4 o;
        o.x = acc[i][0] + bias[n0 + tx * 4 + 0];
        o.y = acc[i][1] + bias[n0 + tx * 4 + 1];
        o.z = acc[i][2] + bias[n0 + tx * 4 + 2];
        o.w = acc[i][3] + bias[n0 + tx * 4 + 3];
        *(float4*)&out[(size_t)m * Dz + n0 + tx * 4] = o;
    }
}

// ---------------- Local softmax attention; writes (1-g)*dot into XT[b][e][l] ----
// grid: (s-half 2, c 8, b*H 64), block 256, thread = one s-row
__global__ __launch_bounds__(256) void attn_kernel(
    const float* __restrict__ q, const float* __restrict__ k, const float* __restrict__ v,
    const float* __restrict__ beta, float* __restrict__ XT)
{
    const int bh = blockIdx.z; const int b = bh >> 4, h = bh & 15;
    const int c = blockIdx.y;
    const int s = blockIdx.x * 256 + threadIdx.x;   // 0..511
    const float g = 1.f / (1.f + __expf(-beta[0]));
    const float scale = 0.125f;

    __shared__ float Ks[64][64];
    __shared__ float Vs[64][64];

    const size_t base = ((size_t)b * Lz + c * Sz) * Dz + h * DHz;
    const float* qrowp = q + base + (size_t)s * Dz;
    float qreg[64];
#pragma unroll
    for (int d = 0; d < 64; d += 4) {
        float4 t = *(const float4*)(qrowp + d);
        qreg[d] = t.x; qreg[d + 1] = t.y; qreg[d + 2] = t.z; qreg[d + 3] = t.w;
    }
    float acc[64];
#pragma unroll
    for (int d = 0; d < 64; ++d) acc[d] = 0.f;
    float lsum = 0.f;

    for (int t0 = 0; t0 < Sz; t0 += 64) {
        __syncthreads();
#pragma unroll
        for (int it = 0; it < 4; ++it) {
            int idx = it * 256 + threadIdx.x;
            int r = idx >> 4, c4 = (idx & 15) * 4;
            *(float4*)&Ks[r][c4] = *(const float4*)(k + base + (size_t)(t0 + r) * Dz + c4);
            *(float4*)&Vs[r][c4] = *(const float4*)(v + base + (size_t)(t0 + r) * Dz + c4);
        }
        __syncthreads();
        for (int t = 0; t < 64; ++t) {
            float logit = 0.f;
#pragma unroll
            for (int d = 0; d < 64; d += 4) {
                float4 kk = *(const float4*)&Ks[t][d];
                logit += qreg[d] * kk.x + qreg[d + 1] * kk.y + qreg[d + 2] * kk.z + qreg[d + 3] * kk.w;
            }
            float p = __expf(logit * scale);
            lsum += p;
#pragma unroll
            for (int d = 0; d < 64; d += 4) {
                float4 vv = *(const float4*)&Vs[t][d];
                acc[d]     += p * vv.x; acc[d + 1] += p * vv.y;
                acc[d + 2] += p * vv.z; acc[d + 3] += p * vv.w;
            }
        }
    }
    const float inv = (1.f - g) / lsum;
    const int e = c * 128 + h * 8 + (s >> 6);
    float* outp = XT + ((size_t)b * Dz + e) * Lz + (s & 63) * 64;
#pragma unroll
    for (int d = 0; d < 64; d += 4) {
        float4 o;
        o.x = acc[d] * inv; o.y = acc[d + 1] * inv; o.z = acc[d + 2] * inv; o.w = acc[d + 3] * inv;
        *(float4*)(outp + d) = o;
    }
}

// ---------------- Memory scan; XT += g*A ----
// grid: 64 blocks (b*H), block 256 = 4 waves; lane = e, wave = row-group
__global__ __launch_bounds__(256) void scan_kernel(
    const float* __restrict__ q, const float* __restrict__ k, const float* __restrict__ v,
    const float* __restrict__ beta, float* __restrict__ XT)
{
    const int bh = blockIdx.x; const int b = bh >> 4, h = bh & 15;
    const int tid = threadIdx.x;
    const int lane = tid & 63;   // e
    const int w = tid >> 6;      // wave 0..3
    const float g = 1.f / (1.f + __expf(-beta[0]));

    __shared__ float sqs[64][64];   // sigma(q) chunk; reused as M-delta exchange
    __shared__ float sks[64][64];   // sigma(k) chunk
    __shared__ float vsb[64][64];   // v chunk, overwritten with val
    __shared__ float sqsum[64];
    __shared__ float sksum[64];

    float Mreg[64];
#pragma unroll
    for (int d = 0; d < 64; ++d) Mreg[d] = 0.f;
    float zreg = 0.f;

    const size_t boff = (size_t)b * Lz * Dz + h * DHz;

    for (int c = 0; c < Cz; ++c) {
        float mdelta[16];
#pragma unroll
        for (int i = 0; i < 16; ++i) mdelta[i] = 0.f;
        float zd = 0.f;

        for (int chunk = 0; chunk < 8; ++chunk) {
            const int s_base = c * Sz + chunk * 64;
            __syncthreads();
#pragma unroll
            for (int it = 0; it < 4; ++it) {
                int idx = it * 256 + tid;
                int r = idx >> 4, c4 = (idx & 15) * 4;
                const size_t go = boff + (size_t)(s_base + r) * Dz + c4;
                float4 tq = *(const float4*)(q + go);
                float4 tk = *(const float4*)(k + go);
                float4 tv = *(const float4*)(v + go);
                sqs[r][c4] = sigmaf(tq.x); sqs[r][c4 + 1] = sigmaf(tq.y);
                sqs[r][c4 + 2] = sigmaf(tq.z); sqs[r][c4 + 3] = sigmaf(tq.w);
                sks[r][c4] = sigmaf(tk.x); sks[r][c4 + 1] = sigmaf(tk.y);
                sks[r][c4 + 2] = sigmaf(tk.z); sks[r][c4 + 3] = sigmaf(tk.w);
                *(float4*)&vsb[r][c4] = tv;
            }
            __syncthreads();
            if (tid < 64) {
                float s1 = 0.f, s2 = 0.f;
#pragma unroll
                for (int d = 0; d < 64; ++d) { s1 += sqs[tid][d]; s2 += sks[tid][d]; }
                sqsum[tid] = s1; sksum[tid] = s2;
            }
            __syncthreads();
            // A and val for 16 rows per wave (uses PRE-update M, z)
            for (int i = 0; i < 16; ++i) {
                const int sl = w * 16 + i;
                float num = 0.f, numk = 0.f;
#pragma unroll
                for (int d = 0; d < 64; ++d) {
                    num  += sqs[sl][d] * Mreg[d];
                    numk += sks[sl][d] * Mreg[d];
                }
                float A   = num  / (sqsum[sl] * zreg + 1e-6f);
                float val = vsb[sl][lane] - numk / (sksum[sl] * zreg + 1e-6f);
                vsb[sl][lane] = val;
                int s_seg = chunk * 64 + sl;
                int e_out = c * 128 + h * 8 + (s_seg >> 6);
                size_t xoff = ((size_t)b * Dz + e_out) * Lz + (size_t)(s_seg & 63) * 64 + lane;
                XT[xoff] += g * A;
            }
            __syncthreads();
            // M-delta (wave w owns rows d = w*16..w*16+15) and z-delta
            for (int sl = 0; sl < 64; ++sl) {
                float vv = vsb[sl][lane];
#pragma unroll
                for (int i = 0; i < 16; ++i)
                    mdelta[i] += sks[sl][w * 16 + i] * vv;
                zd += sks[sl][lane];
            }
        }
        // apply deltas via LDS exchange (alias onto sqs)
        __syncthreads();
#pragma unroll
        for (int i = 0; i < 16; ++i) sqs[w * 16 + i][lane] = mdelta[i];
        __syncthreads();
#pragma unroll
        for (int d = 0; d < 64; ++d) Mreg[d] += sqs[d][lane];
        zreg += zd;
    }
}

// ---------------- Output GEMM: out[b,l,n] = sum_e XT[b,e,l]*Wo[e,n] + bo[n] ----
__global__ __launch_bounds__(256) void out_gemm(
    const float* __restrict__ XT, const float* __restrict__ Wo,
    const float* __restrict__ bo, float* __restrict__ out)
{
    const int b = blockIdx.z;
    const int n0 = blockIdx.x * 64;
    const int l0 = blockIdx.y * 64;
    __shared__ float As[16][64];   // [e][l]
    __shared__ float Bs[16][64];   // [e][n]
    const int tid = threadIdx.x;
    const int tx = tid & 15, ty = tid >> 4;
    float acc[4][4] = {{0.f}};
    const int ar = tid >> 4;
    const int ac = (tid & 15) * 4;
    const float* Xb = XT + (size_t)b * Dz * Lz;

    for (int k0 = 0; k0 < Dz; k0 += 16) {
        float4 a  = *(const float4*)&Xb[(size_t)(k0 + ar) * Lz + l0 + ac];
        float4 b4 = *(const float4*)&Wo[(size_t)(k0 + ar) * Dz + n0 + ac];
        __syncthreads();
        *(float4*)&As[ar][ac] = a;
        *(float4*)&Bs[ar][ac] = b4;
        __syncthreads();
#pragma unroll
        for (int kk = 0; kk < 16; ++kk) {
            float av[4], bv4[4];
            *(float4*)av  = *(const float4*)&As[kk][ty * 4];
            *(float4*)bv4 = *(const float4*)&Bs[kk][tx * 4];
#pragma unroll
            for (int i = 0; i < 4; ++i)
#pragma unroll
                for (int j = 0; j < 4; ++j) acc[i][j] += av[i] * bv4[j];
        }
    }
#pragma unroll
    for (int i = 0; i < 4; ++i) {
        int l = l0 + ty * 4 + i;
        float4 o;
        o.x = acc[i][0] + bo[n0 + tx * 4 + 0];
        o.y = acc[i][1] + bo[n0 + tx * 4 + 1];
        o.z = acc[i][2] + bo[n0 + tx * 4 + 2];
        o.w = acc[i][3] + bo[n0 + tx * 4 + 3];
        *(float4*)&out[((size_t)b * Lz + l) * Dz + n0 + tx * 4] = o;
    }
}

extern "C" void kernel_launch(void* const* d_in, const int* in_sizes, int n_in,
                              void* d_out, int out_size, void* d_ws, size_t ws_size,
                              hipStream_t stream)
{
    (void)in_sizes; (void)n_in; (void)out_size;
    const float* query  = (const float*)d_in[0];
    const float* key_in = (const float*)d_in[1];
    const float* value  = (const float*)d_in[2];
    const float* Wq = (const float*)d_in[3];
    const float* bq = (const float*)d_in[4];
    const float* Wk = (const float*)d_in[5];
    const float* bk = (const float*)d_in[6];
    const float* Wv = (const float*)d_in[7];
    const float* bv = (const float*)d_in[8];
    const float* Wo = (const float*)d_in[9];
    const float* bo = (const float*)d_in[10];
    const float* beta = (const float*)d_in[11];
    float* out = (float*)d_out;

    const size_t NE = (size_t)Bz * Lz * Dz;   // 16,777,216 elements per buffer
    float* qb = (float*)d_ws;
    float* kb = qb + NE;
    float* vb = kb + NE;
    const bool big = ws_size >= 4 * NE * sizeof(float);
    float* XT = big ? (vb + NE) : (float*)d_out;

    proj_kernel<<<dim3(16, 256, 3), 256, 0, stream>>>(query, key_in, value,
                                                      Wq, bq, Wk, bk, Wv, bv, qb, kb, vb);
    attn_kernel<<<dim3(2, Cz, Bz * Hz), 256, 0, stream>>>(qb, kb, vb, beta, XT);
    scan_kernel<<<dim3(Bz * Hz), 256, 0, stream>>>(qb, kb, vb, beta, XT);
    if (big) {
        out_gemm<<<dim3(16, 64, Bz), 256, 0, stream>>>(XT, Wo, bo, out);
    } else {
        out_gemm<<<dim3(16, 64, Bz), 256, 0, stream>>>(XT, Wo, bo, qb);
        hipMemcpyAsync(out, qb, NE * sizeof(float), hipMemcpyDeviceToDevice, stream);
    }
}

// Round 2
// 3854.526 us; speedup vs baseline: 1.3114x; 1.3114x over previous
//
#include <hip/hip_runtime.h>
#include <math.h>

#define Bz 4
#define Lz 4096
#define Dz 1024
#define Hz 16
#define Cz 8
#define Sz 512
#define DHz 64

__device__ __forceinline__ float sigmaf(float x) {
    return x >= 0.f ? x : expm1f(x);
}

// ---------------- QKV projection: out = X @ W + b  (3 GEMMs via blockIdx.z) ----
__global__ __launch_bounds__(256) void proj_kernel(
    const float* __restrict__ Xq, const float* __restrict__ Xk, const float* __restrict__ Xv,
    const float* __restrict__ Wq, const float* __restrict__ bq,
    const float* __restrict__ Wk, const float* __restrict__ bk,
    const float* __restrict__ Wv, const float* __restrict__ bv,
    float* __restrict__ outq, float* __restrict__ outk, float* __restrict__ outv)
{
    const int which = blockIdx.z;
    const float* __restrict__ X = which == 0 ? Xq : (which == 1 ? Xk : Xv);
    const float* __restrict__ W = which == 0 ? Wq : (which == 1 ? Wk : Wv);
    const float* __restrict__ bias = which == 0 ? bq : (which == 1 ? bk : bv);
    float* __restrict__ out = which == 0 ? outq : (which == 1 ? outk : outv);

    __shared__ float As[16][64];   // [k][m]
    __shared__ float Bs[16][64];   // [k][n]
    const int tid = threadIdx.x;
    const int m0 = blockIdx.y * 64;
    const int n0 = blockIdx.x * 64;
    const int tx = tid & 15, ty = tid >> 4;

    float acc[4][4] = {{0.f}};

    const int lm = tid >> 2;          // A row 0..63
    const int lk = (tid & 3) * 4;     // A k 0,4,8,12
    const int br = tid >> 4;          // B row 0..15
    const int bn = (tid & 15) * 4;    // B col

    for (int k0 = 0; k0 < Dz; k0 += 16) {
        float4 a = *(const float4*)&X[(size_t)(m0 + lm) * Dz + k0 + lk];
        float4 b4 = *(const float4*)&W[(size_t)(k0 + br) * Dz + n0 + bn];
        __syncthreads();
        As[lk + 0][lm] = a.x; As[lk + 1][lm] = a.y; As[lk + 2][lm] = a.z; As[lk + 3][lm] = a.w;
        *(float4*)&Bs[br][bn] = b4;
        __syncthreads();
#pragma unroll
        for (int kk = 0; kk < 16; ++kk) {
            float av[4], bv4[4];
            *(float4*)av  = *(const float4*)&As[kk][ty * 4];
            *(float4*)bv4 = *(const float4*)&Bs[kk][tx * 4];
#pragma unroll
            for (int i = 0; i < 4; ++i)
#pragma unroll
                for (int j = 0; j < 4; ++j) acc[i][j] += av[i] * bv4[j];
        }
    }
#pragma unroll
    for (int i = 0; i < 4; ++i) {
        int m = m0 + ty * 4 + i;
        float4 o;
        o.x = acc[i][0] + bias[n0 + tx * 4 + 0];
        o.y = acc[i][1] + bias[n0 + tx * 4 + 1];
        o.z = acc[i][2] + bias[n0 + tx * 4 + 2];
        o.w = acc[i][3] + bias[n0 + tx * 4 + 3];
        *(float4*)&out[(size_t)m * Dz + n0 + tx * 4] = o;
    }
}

// ---------------- Local softmax attention; writes (1-g)*dot into XT[b][e][l] ----
__global__ __launch_bounds__(256) void attn_kernel(
    const float* __restrict__ q, const float* __restrict__ k, const float* __restrict__ v,
    const float* __restrict__ beta, float* __restrict__ XT)
{
    const int bh = blockIdx.z; const int b = bh >> 4, h = bh & 15;
    const int c = blockIdx.y;
    const int s = blockIdx.x * 256 + threadIdx.x;   // 0..511
    const float g = 1.f / (1.f + __expf(-beta[0]));
    const float scale = 0.125f;

    __shared__ float Ks[64][64];
    __shared__ float Vs[64][64];

    const size_t base = ((size_t)b * Lz + c * Sz) * Dz + h * DHz;
    const float* qrowp = q + base + (size_t)s * Dz;
    float qreg[64];
#pragma unroll
    for (int d = 0; d < 64; d += 4) {
        float4 t = *(const float4*)(qrowp + d);
        qreg[d] = t.x; qreg[d + 1] = t.y; qreg[d + 2] = t.z; qreg[d + 3] = t.w;
    }
    float acc[64];
#pragma unroll
    for (int d = 0; d < 64; ++d) acc[d] = 0.f;
    float lsum = 0.f;

    for (int t0 = 0; t0 < Sz; t0 += 64) {
        __syncthreads();
#pragma unroll
        for (int it = 0; it < 4; ++it) {
            int idx = it * 256 + threadIdx.x;
            int r = idx >> 4, c4 = (idx & 15) * 4;
            *(float4*)&Ks[r][c4] = *(const float4*)(k + base + (size_t)(t0 + r) * Dz + c4);
            *(float4*)&Vs[r][c4] = *(const float4*)(v + base + (size_t)(t0 + r) * Dz + c4);
        }
        __syncthreads();
        for (int t = 0; t < 64; ++t) {
            float logit = 0.f;
#pragma unroll
            for (int d = 0; d < 64; d += 4) {
                float4 kk = *(const float4*)&Ks[t][d];
                logit += qreg[d] * kk.x + qreg[d + 1] * kk.y + qreg[d + 2] * kk.z + qreg[d + 3] * kk.w;
            }
            float p = __expf(logit * scale);
            lsum += p;
#pragma unroll
            for (int d = 0; d < 64; d += 4) {
                float4 vv = *(const float4*)&Vs[t][d];
                acc[d]     += p * vv.x; acc[d + 1] += p * vv.y;
                acc[d + 2] += p * vv.z; acc[d + 3] += p * vv.w;
            }
        }
    }
    const float inv = (1.f - g) / lsum;
    const int e = c * 128 + h * 8 + (s >> 6);
    float* outp = XT + ((size_t)b * Dz + e) * Lz + (s & 63) * 64;
#pragma unroll
    for (int d = 0; d < 64; d += 4) {
        float4 o;
        o.x = acc[d] * inv; o.y = acc[d + 1] * inv; o.z = acc[d + 2] * inv; o.w = acc[d + 3] * inv;
        *(float4*)(outp + d) = o;
    }
}

// ---------------- Scan phase 1: evolve M,z; store per-segment prefixes ----
// grid: 256 blocks = bh(64) x esplit(4); block 256 threads.
// thread: el = tid&15 (e-col within 16-col slice), rs = tid>>4 (row group / d group)
__global__ __launch_bounds__(256) void scan_s1(
    const float* __restrict__ k, const float* __restrict__ v,
    float* __restrict__ Mpre, float* __restrict__ zpre)
{
    const int bx = blockIdx.x;
    const int bh = bx >> 2, es = bx & 3;
    const int b = bh >> 4, h = bh & 15;
    const int tid = threadIdx.x;
    const int el = tid & 15;          // e-local 0..15
    const int rs = tid >> 4;          // 0..15
    const int eg = es * 16 + el;      // e within head, 0..63

    __shared__ float ks[64][68];      // sigma(k) rows, padded (+4) -> conflict-free
    __shared__ float vs2[64][16];     // v slice, later holds val, later mdelta exchange

    float Mreg[64];                   // column eg of M
#pragma unroll
    for (int d = 0; d < 64; ++d) Mreg[d] = 0.f;
    float zreg = 0.f;

    const size_t boff = (size_t)b * Lz * Dz + h * DHz;

    for (int c = 0; c < Cz; ++c) {
        // store prefix (pre-segment M, z) for S2
        {
            float* mp = Mpre + ((size_t)(bh * Cz + c) * 64) * 64;
#pragma unroll
            for (int j = 0; j < 4; ++j) {
                int d = rs * 4 + j;
                mp[(size_t)d * 64 + eg] = Mreg[d];
            }
            if (rs == 0) zpre[(size_t)(bh * Cz + c) * 64 + eg] = zreg;
        }
        float mdelta[4] = {0.f, 0.f, 0.f, 0.f};
        float zd = 0.f;

        for (int ch = 0; ch < 8; ++ch) {
            const int s0 = c * Sz + ch * 64;
            __syncthreads();
            // stage sigma(k): 64 rows x 64 d
#pragma unroll
            for (int it = 0; it < 4; ++it) {
                int idx = it * 256 + tid;
                int r = idx >> 4, f = (idx & 15) * 4;
                float4 t = *(const float4*)(k + boff + (size_t)(s0 + r) * Dz + f);
                ks[r][f + 0] = sigmaf(t.x); ks[r][f + 1] = sigmaf(t.y);
                ks[r][f + 2] = sigmaf(t.z); ks[r][f + 3] = sigmaf(t.w);
            }
            // stage v slice: 64 rows x 16 cols (this block's e-range)
            {
                int r = tid >> 2, f = (tid & 3) * 4;
                float4 t = *(const float4*)(v + boff + (size_t)(s0 + r) * Dz + es * 16 + f);
                *(float4*)&vs2[r][f] = t;
            }
            __syncthreads();
            // val = v - (sigma(k)@M)/(ssk*z+eps), each thread owns (sl=rs*4+j, el)
#pragma unroll
            for (int j = 0; j < 4; ++j) {
                const int sl = rs * 4 + j;
                float numk = 0.f, ssk = 0.f;
#pragma unroll
                for (int d = 0; d < 64; d += 4) {
                    float4 kk = *(const float4*)&ks[sl][d];
                    numk += kk.x * Mreg[d] + kk.y * Mreg[d + 1]
                          + kk.z * Mreg[d + 2] + kk.w * Mreg[d + 3];
                    ssk += kk.x + kk.y + kk.z + kk.w;
                }
                vs2[sl][el] = vs2[sl][el] - numk / (ssk * zreg + 1e-6f);
            }
            __syncthreads();
            // mdelta[d=rs*4+j][eg] += sum_sl sigma(k)[sl][d]*val[sl][eg]; also z delta
            for (int sl = 0; sl < 64; ++sl) {
                float vv = vs2[sl][el];
                float4 kk = *(const float4*)&ks[sl][rs * 4];
                mdelta[0] += kk.x * vv; mdelta[1] += kk.y * vv;
                mdelta[2] += kk.z * vv; mdelta[3] += kk.w * vv;
                zd += ks[sl][eg];
            }
        }
        // apply deltas: exchange mdelta columns via vs2
        __syncthreads();
#pragma unroll
        for (int j = 0; j < 4; ++j) vs2[rs * 4 + j][el] = mdelta[j];
        __syncthreads();
#pragma unroll
        for (int d = 0; d < 64; ++d) Mreg[d] += vs2[d][el];
        zreg += zd;
    }
}

// ---------------- Scan phase 2: A-readout from prefixes; XT += g*A ----
// grid: (tile 8, c 8, bh 64); block 256 = 4 waves; lane = e, wave -> 16 rows
__global__ __launch_bounds__(256) void scan_s2(
    const float* __restrict__ q, const float* __restrict__ Mpre,
    const float* __restrict__ zpre, const float* __restrict__ beta,
    float* __restrict__ XT)
{
    const int bh = blockIdx.z; const int b = bh >> 4, h = bh & 15;
    const int c = blockIdx.y;
    const int tile = blockIdx.x;          // 0..7
    const int tid = threadIdx.x;
    const int lane = tid & 63;            // e
    const int w = tid >> 6;               // wave 0..3
    const float g = 1.f / (1.f + __expf(-beta[0]));

    __shared__ float qs[64][68];

    float Mreg[64];
    const float* mp = Mpre + ((size_t)(bh * Cz + c) * 64) * 64;
#pragma unroll
    for (int d = 0; d < 64; ++d) Mreg[d] = mp[(size_t)d * 64 + lane];
    const float zv = zpre[(size_t)(bh * Cz + c) * 64 + lane];

    const size_t boff = (size_t)b * Lz * Dz + h * DHz;
    const int s0 = c * Sz + tile * 64;
#pragma unroll
    for (int it = 0; it < 4; ++it) {
        int idx = it * 256 + tid;
        int r = idx >> 4, f = (idx & 15) * 4;
        float4 t = *(const float4*)(q + boff + (size_t)(s0 + r) * Dz + f);
        qs[r][f + 0] = sigmaf(t.x); qs[r][f + 1] = sigmaf(t.y);
        qs[r][f + 2] = sigmaf(t.z); qs[r][f + 3] = sigmaf(t.w);
    }
    __syncthreads();

    const int e_out = c * 128 + h * 8 + tile;
    float* xp = XT + ((size_t)b * Dz + e_out) * Lz;
    for (int i = 0; i < 16; ++i) {
        const int sl = w * 16 + i;
        float num = 0.f, ssq = 0.f;
#pragma unroll
        for (int d = 0; d < 64; d += 4) {
            float4 qq = *(const float4*)&qs[sl][d];
            num += qq.x * Mreg[d] + qq.y * Mreg[d + 1]
                 + qq.z * Mreg[d + 2] + qq.w * Mreg[d + 3];
            ssq += qq.x + qq.y + qq.z + qq.w;
        }
        float A = num / (ssq * zv + 1e-6f);
        size_t xoff = (size_t)sl * 64 + lane;
        xp[xoff] += g * A;
    }
}

// ---------------- Output GEMM: out[b,l,n] = sum_e XT[b,e,l]*Wo[e,n] + bo[n] ----
__global__ __launch_bounds__(256) void out_gemm(
    const float* __restrict__ XT, const float* __restrict__ Wo,
    const float* __restrict__ bo, float* __restrict__ out)
{
    const int b = blockIdx.z;
    const int n0 = blockIdx.x * 64;
    const int l0 = blockIdx.y * 64;
    __shared__ float As[16][64];   // [e][l]
    __shared__ float Bs[16][64];   // [e][n]
    const int tid = threadIdx.x;
    const int tx = tid & 15, ty = tid >> 4;
    float acc[4][4] = {{0.f}};
    const int ar = tid >> 4;
    const int ac = (tid & 15) * 4;
    const float* Xb = XT + (size_t)b * Dz * Lz;

    for (int k0 = 0; k0 < Dz; k0 += 16) {
        float4 a  = *(const float4*)&Xb[(size_t)(k0 + ar) * Lz + l0 + ac];
        float4 b4 = *(const float4*)&Wo[(size_t)(k0 + ar) * Dz + n0 + ac];
        __syncthreads();
        *(float4*)&As[ar][ac] = a;
        *(float4*)&Bs[ar][ac] = b4;
        __syncthreads();
#pragma unroll
        for (int kk = 0; kk < 16; ++kk) {
            float av[4], bv4[4];
            *(float4*)av  = *(const float4*)&As[kk][ty * 4];
            *(float4*)bv4 = *(const float4*)&Bs[kk][tx * 4];
#pragma unroll
            for (int i = 0; i < 4; ++i)
#pragma unroll
                for (int j = 0; j < 4; ++j) acc[i][j] += av[i] * bv4[j];
        }
    }
#pragma unroll
    for (int i = 0; i < 4; ++i) {
        int l = l0 + ty * 4 + i;
        float4 o;
        o.x = acc[i][0] + bo[n0 + tx * 4 + 0];
        o.y = acc[i][1] + bo[n0 + tx * 4 + 1];
        o.z = acc[i][2] + bo[n0 + tx * 4 + 2];
        o.w = acc[i][3] + bo[n0 + tx * 4 + 3];
        *(float4*)&out[((size_t)b * Lz + l) * Dz + n0 + tx * 4] = o;
    }
}

extern "C" void kernel_launch(void* const* d_in, const int* in_sizes, int n_in,
                              void* d_out, int out_size, void* d_ws, size_t ws_size,
                              hipStream_t stream)
{
    (void)in_sizes; (void)n_in; (void)out_size;
    const float* query  = (const float*)d_in[0];
    const float* key_in = (const float*)d_in[1];
    const float* value  = (const float*)d_in[2];
    const float* Wq = (const float*)d_in[3];
    const float* bq = (const float*)d_in[4];
    const float* Wk = (const float*)d_in[5];
    const float* bk = (const float*)d_in[6];
    const float* Wv = (const float*)d_in[7];
    const float* bv = (const float*)d_in[8];
    const float* Wo = (const float*)d_in[9];
    const float* bo = (const float*)d_in[10];
    const float* beta = (const float*)d_in[11];
    float* out = (float*)d_out;

    const size_t NE = (size_t)Bz * Lz * Dz;            // 16,777,216 per buffer
    const size_t NM = (size_t)64 * Cz * 64 * 64;       // M prefixes: 2,097,152
    const size_t NZ = (size_t)64 * Cz * 64;            // z prefixes: 32,768
    float* qb = (float*)d_ws;
    float* kb = qb + NE;
    float* vb = kb + NE;
    float* Mpre = vb + NE;
    float* zpre = Mpre + NM;
    const bool big = ws_size >= (4 * NE + NM + NZ) * sizeof(float);
    float* XT = big ? (zpre + NZ) : (float*)d_out;

    proj_kernel<<<dim3(16, 256, 3), 256, 0, stream>>>(query, key_in, value,
                                                      Wq, bq, Wk, bk, Wv, bv, qb, kb, vb);
    attn_kernel<<<dim3(2, Cz, Bz * Hz), 256, 0, stream>>>(qb, kb, vb, beta, XT);
    scan_s1<<<dim3(256), 256, 0, stream>>>(kb, vb, Mpre, zpre);
    scan_s2<<<dim3(8, Cz, Bz * Hz), 256, 0, stream>>>(qb, Mpre, zpre, beta, XT);
    if (big) {
        out_gemm<<<dim3(16, 64, Bz), 256, 0, stream>>>(XT, Wo, bo, out);
    } else {
        out_gemm<<<dim3(16, 64, Bz), 256, 0, stream>>>(XT, Wo, bo, qb);
        hipMemcpyAsync(out, qb, NE * sizeof(float), hipMemcpyDeviceToDevice, stream);
    }
}